// Round 1
// baseline (1210.128 us; speedup 1.0000x reference)
//
#include <hip/hip_runtime.h>

// TopKRouter: B=4,S=4096,D=4096,E=64,K=2  (tokens=16384)
// logits = x @ W^T ; probs = softmax(logits); top-2 (probs, indices, values)
// Output buffer (all read back as float32): [probs 16384*64][idx 16384*2][val 16384*2]

#define TOK 16384
#define DIM 4096
#define NE 64
#define NW 8              // waves per block == K-slices
#define KS (DIM / NW)     // 512 dims per wave
#define IDX_OFF (TOK * NE)
#define VAL_OFF (IDX_OFF + TOK * 2)

__global__ __launch_bounds__(512)
void router_kernel(const float* __restrict__ x,
                   const float* __restrict__ W,
                   float* __restrict__ out)
{
    __shared__ float red[4 * NE * 64];   // 64 KB, tree-reduction buffer

    const int lane = threadIdx.x & 63;
    const int wid  = __builtin_amdgcn_readfirstlane(threadIdx.x >> 6); // force wave-uniform
    const int t0   = blockIdx.x * 64;
    const int t    = t0 + lane;          // this lane's token

    // lane-private x row slice; wave-uniform W slice (scalar loads)
    const float* xp = x + (size_t)t * DIM + wid * KS;
    const float* wp = W + wid * KS;      // W[e][d] row-major: wp + e*DIM + d

    float acc[NE];
#pragma unroll
    for (int e = 0; e < NE; ++e) acc[e] = 0.f;

    // K-loop over this wave's 512-dim slice, 8 dims per iteration.
    // x: 2x b128 per-lane loads; W: 64x s_load_dwordx8 (uniform) per iteration;
    // 512 v_fmac per lane per iteration (1 SGPR operand each).
    for (int d0 = 0; d0 < KS; d0 += 8) {
        const float4 a = *(const float4*)(xp + d0);
        const float4 b = *(const float4*)(xp + d0 + 4);
#pragma unroll
        for (int e = 0; e < NE; ++e) {
            const float* w8 = wp + e * DIM + d0;
            float s = acc[e];
            s = fmaf(a.x, w8[0], s);
            s = fmaf(a.y, w8[1], s);
            s = fmaf(a.z, w8[2], s);
            s = fmaf(a.w, w8[3], s);
            s = fmaf(b.x, w8[4], s);
            s = fmaf(b.y, w8[5], s);
            s = fmaf(b.z, w8[6], s);
            s = fmaf(b.w, w8[7], s);
            acc[e] = s;
        }
    }

    // ---- binary-tree cross-wave reduction through LDS ----
    // layout red[region][e*64 + lane]: lanes consecutive -> 2 lanes/bank (free)
    if (wid >= 4) {
#pragma unroll
        for (int e = 0; e < NE; ++e) red[(wid - 4) * (NE * 64) + e * 64 + lane] = acc[e];
    }
    __syncthreads();
    if (wid < 4) {
#pragma unroll
        for (int e = 0; e < NE; ++e) acc[e] += red[wid * (NE * 64) + e * 64 + lane];
    }
    __syncthreads();
    if (wid == 2 || wid == 3) {
#pragma unroll
        for (int e = 0; e < NE; ++e) red[(wid - 2) * (NE * 64) + e * 64 + lane] = acc[e];
    }
    __syncthreads();
    if (wid < 2) {
#pragma unroll
        for (int e = 0; e < NE; ++e) acc[e] += red[wid * (NE * 64) + e * 64 + lane];
    }
    __syncthreads();
    if (wid == 1) {
#pragma unroll
        for (int e = 0; e < NE; ++e) red[e * 64 + lane] = acc[e];
    }
    __syncthreads();

    if (wid == 0) {
#pragma unroll
        for (int e = 0; e < NE; ++e) acc[e] += red[e * 64 + lane];

        // ---- softmax over 64 experts, fully per-lane ----
        float m = acc[0];
#pragma unroll
        for (int e = 1; e < NE; ++e) m = fmaxf(m, acc[e]);
        float sum = 0.f;
#pragma unroll
        for (int e = 0; e < NE; ++e) sum += __expf(acc[e] - m);
        const float inv = 1.f / sum;

        // ---- probs write + top-2 scan (ascending index => lax.top_k tie-break) ----
        float v1 = -1.f, v2 = -1.f;
        int   i1 = 0,    i2 = 0;
        float* probs = out + (size_t)t * NE;
#pragma unroll
        for (int e0 = 0; e0 < NE; e0 += 4) {
            float4 pv;
            float* pp = &pv.x;
#pragma unroll
            for (int j = 0; j < 4; ++j) {
                const int e = e0 + j;
                const float p = __expf(acc[e] - m) * inv;
                pp[j] = p;
                if (p > v1)      { v2 = v1; i2 = i1; v1 = p; i1 = e; }
                else if (p > v2) { v2 = p;  i2 = e; }
            }
            *(float4*)(probs + e0) = pv;
        }

        out[IDX_OFF + (size_t)t * 2]     = (float)i1;
        out[IDX_OFF + (size_t)t * 2 + 1] = (float)i2;
        out[VAL_OFF + (size_t)t * 2]     = v1;
        out[VAL_OFF + (size_t)t * 2 + 1] = v2;
    }
}

extern "C" void kernel_launch(void* const* d_in, const int* in_sizes, int n_in,
                              void* d_out, int out_size, void* d_ws, size_t ws_size,
                              hipStream_t stream) {
    const float* x = (const float*)d_in[0];
    const float* W = (const float*)d_in[1];
    (void)in_sizes; (void)n_in; (void)d_ws; (void)ws_size; (void)out_size;
    float* out = (float*)d_out;

    router_kernel<<<TOK / 64, 512, 0, stream>>>(x, W, out);
}

// Round 2
// 992.126 us; speedup vs baseline: 1.2197x; 1.2197x over previous
//
#include <hip/hip_runtime.h>

// TopKRouter: B=4,S=4096,D=4096,E=64,K=2  (tokens=16384)
// logits = x @ W^T ; probs = softmax(logits); top-2 (probs, indices, values)
// Out layout (read back as f32): [probs 16384*64][idx 16384*2][val 16384*2]
//
// R2 structure: 256 blocks x 512 threads (8 waves). Block owns 64 tokens
// (lane = token). Experts split across waves (8/wave -> acc[8], no spill;
// R1's acc[64] spilled: VGPR_Count=52 < 64 accumulators).
// x staged through LDS in 64x128 tiles (read from HBM once); W via wave-
// uniform scalar loads. Register prefetch pipeline hides HBM latency.

#define TOK 16384
#define DIM 4096
#define NE 64
#define NW 8                 // waves per block
#define NEPW (NE / NW)       // 8 experts per wave
#define KT 128               // K-tile (dims)
#define NT (DIM / KT)        // 32 tiles
#define ROW 132              // LDS row stride (floats): 16B-aligned, bank-rotated
#define EROW 68              // epilogue logit row stride (floats), 16B-aligned
#define IDX_OFF (TOK * NE)
#define VAL_OFF (IDX_OFF + TOK * 2)

__global__ __launch_bounds__(512)
void router_kernel(const float* __restrict__ x,
                   const float* __restrict__ W,
                   float* __restrict__ out)
{
    __shared__ __align__(16) float xs[64 * ROW];   // 33792 B

    const int tid  = threadIdx.x;
    const int lane = tid & 63;
    const int wid  = __builtin_amdgcn_readfirstlane(tid >> 6);  // wave-uniform
    const int t0   = blockIdx.x * 64;

    // staging coords: thread -> (token, 16B chunk); wave covers 8 tokens x 32B
    const int stok = tid >> 3;           // 0..63
    const int sc   = (tid & 7) * 4;      // float offset within 32-float pass
    const float* xrow = x + (size_t)(t0 + stok) * DIM;

    // compute coords: this wave's 8 experts (uniform -> scalar loads for W)
    const int e0 = wid * NEPW;
    const float* wbase = W + (size_t)e0 * DIM;

    float acc[NEPW];
#pragma unroll
    for (int j = 0; j < NEPW; ++j) acc[j] = 0.f;

    // prologue: prefetch tile 0 into registers
    float4 pf[4];
#pragma unroll
    for (int p = 0; p < 4; ++p)
        pf[p] = *(const float4*)(xrow + p * 32 + sc);

    for (int t = 0; t < NT; ++t) {
        __syncthreads();                         // everyone done reading tile t-1
#pragma unroll
        for (int p = 0; p < 4; ++p)
            *(float4*)(&xs[stok * ROW + p * 32 + sc]) = pf[p];
        __syncthreads();                         // tile t visible

        if (t + 1 < NT) {                        // issue next-tile loads early;
            const float* src = xrow + (t + 1) * KT;  // consumed after full compute phase
#pragma unroll
            for (int p = 0; p < 4; ++p)
                pf[p] = *(const float4*)(src + p * 32 + sc);
        }

        const float* wt = wbase + t * KT;        // uniform
        const float* xl = &xs[lane * ROW];       // 16B-aligned per lane
#pragma unroll 4
        for (int d0 = 0; d0 < KT; d0 += 4) {
            const float4 xv = *(const float4*)(xl + d0);   // ds_read_b128
#pragma unroll
            for (int j = 0; j < NEPW; ++j) {     // 8 independent fma chains
                const float* wr = wt + (size_t)j * DIM + d0;  // s_load_dwordx4
                float s = acc[j];
                s = fmaf(xv.x, wr[0], s);
                s = fmaf(xv.y, wr[1], s);
                s = fmaf(xv.z, wr[2], s);
                s = fmaf(xv.w, wr[3], s);
                acc[j] = s;
            }
        }
    }

    // ---- epilogue: gather logits in LDS, wave 0 does softmax + top-2 ----
    __syncthreads();                 // done with xs as x-tile
    float* lgt = xs;                 // reuse: [64 tok][EROW]
    {
        float4 a = make_float4(acc[0], acc[1], acc[2], acc[3]);
        float4 b = make_float4(acc[4], acc[5], acc[6], acc[7]);
        *(float4*)(&lgt[lane * EROW + e0])     = a;   // ds_write_b128
        *(float4*)(&lgt[lane * EROW + e0 + 4]) = b;
    }
    __syncthreads();

    if (wid == 0) {
        const int tkn = t0 + lane;
        const float* lr = &lgt[lane * EROW];

        float m = -3.0e38f;
#pragma unroll
        for (int e4 = 0; e4 < NE; e4 += 4) {
            const float4 v = *(const float4*)(lr + e4);
            m = fmaxf(m, fmaxf(fmaxf(v.x, v.y), fmaxf(v.z, v.w)));
        }
        float sum = 0.f;
#pragma unroll
        for (int e4 = 0; e4 < NE; e4 += 4) {
            const float4 v = *(const float4*)(lr + e4);
            sum += __expf(v.x - m) + __expf(v.y - m)
                 + __expf(v.z - m) + __expf(v.w - m);
        }
        const float inv = 1.f / sum;

        float v1 = -1.f, v2 = -1.f;
        int   i1 = 0,    i2 = 0;
        float* probs = out + (size_t)tkn * NE;
#pragma unroll
        for (int e4 = 0; e4 < NE; e4 += 4) {
            const float4 v = *(const float4*)(lr + e4);
            float4 pv;
            pv.x = __expf(v.x - m) * inv;
            pv.y = __expf(v.y - m) * inv;
            pv.z = __expf(v.z - m) * inv;
            pv.w = __expf(v.w - m) * inv;
            const float* pp = &pv.x;
#pragma unroll
            for (int q = 0; q < 4; ++q) {        // ascending e => lax.top_k tie-break
                const int e = e4 + q;
                const float p = pp[q];
                if (p > v1)      { v2 = v1; i2 = i1; v1 = p; i1 = e; }
                else if (p > v2) { v2 = p;  i2 = e; }
            }
            *(float4*)(probs + e4) = pv;
        }

        out[IDX_OFF + (size_t)tkn * 2]     = (float)i1;
        out[IDX_OFF + (size_t)tkn * 2 + 1] = (float)i2;
        out[VAL_OFF + (size_t)tkn * 2]     = v1;
        out[VAL_OFF + (size_t)tkn * 2 + 1] = v2;
    }
}

extern "C" void kernel_launch(void* const* d_in, const int* in_sizes, int n_in,
                              void* d_out, int out_size, void* d_ws, size_t ws_size,
                              hipStream_t stream) {
    const float* x = (const float*)d_in[0];
    const float* W = (const float*)d_in[1];
    (void)in_sizes; (void)n_in; (void)d_ws; (void)ws_size; (void)out_size;
    float* out = (float*)d_out;

    router_kernel<<<TOK / 64, 512, 0, stream>>>(x, W, out);
}

// Round 3
// 504.751 us; speedup vs baseline: 2.3975x; 1.9656x over previous
//
#include <hip/hip_runtime.h>

// TopKRouter: B=4,S=4096,D=4096,E=64,K=2 (tokens=16384)
// R3: split-bf16 MFMA. fp32 = hi(bf16,trunc) + lo(bf16); x@W^T via
// 3x mfma_f32_16x16x32_bf16 (hi*HI + lo*HI + hi*LO), fp32 accumulate.
// Wave = 16 tokens x 16 experts; block = 4 waves (16 tok x 64 experts);
// grid = 1024. W pre-split into d_ws (packed bf16 hi/lo, 1 MB, L2-hot)
// by wconv_kernel. R2 lesson: W cannot stream through SGPRs.

#define TOK 16384
#define DIM 4096
#define NE  64
#define IDX_OFF (TOK * NE)
#define VAL_OFF (IDX_OFF + TOK * 2)
#define WELTS (NE * DIM)            // 262144

typedef __attribute__((ext_vector_type(8))) short short8;
typedef __attribute__((ext_vector_type(4))) float f32x4;

union pk8u { unsigned int u[4]; short8 s; };

// (fa,fb) -> packed bf16 pair hi (truncate) and lo (exact residual, truncate)
__device__ __forceinline__ void split_pair(float fa, float fb,
                                           unsigned int& hpk, unsigned int& lpk) {
    unsigned int ua = __float_as_uint(fa), ub = __float_as_uint(fb);
    hpk = __builtin_amdgcn_perm(ub, ua, 0x07060302u);          // [fa.hi16, fb.hi16]
    float la = fa - __uint_as_float(ua & 0xffff0000u);         // exact
    float lb = fb - __uint_as_float(ub & 0xffff0000u);         // exact
    lpk = __builtin_amdgcn_perm(__float_as_uint(lb), __float_as_uint(la), 0x07060302u);
}

__device__ __forceinline__ void split8(const float4 v0, const float4 v1,
                                       short8& hi, short8& lo) {
    pk8u h, l;
    split_pair(v0.x, v0.y, h.u[0], l.u[0]);
    split_pair(v0.z, v0.w, h.u[1], l.u[1]);
    split_pair(v1.x, v1.y, h.u[2], l.u[2]);
    split_pair(v1.z, v1.w, h.u[3], l.u[3]);
    hi = h.s; lo = l.s;
}

__device__ __forceinline__ void mfma3(f32x4& acc, const float4 a0, const float4 a1,
                                      const short8 bh, const short8 bl) {
    short8 ah, al;
    split8(a0, a1, ah, al);
    acc = __builtin_amdgcn_mfma_f32_16x16x32_bf16(ah, bh, acc, 0, 0, 0);
    acc = __builtin_amdgcn_mfma_f32_16x16x32_bf16(al, bh, acc, 0, 0, 0);
    acc = __builtin_amdgcn_mfma_f32_16x16x32_bf16(ah, bl, acc, 0, 0, 0);
}

// pre-split W (64x4096 fp32 -> packed bf16 hi + lo arrays in ws)
__global__ __launch_bounds__(256)
void wconv_kernel(const float* __restrict__ W,
                  unsigned int* __restrict__ whi, unsigned int* __restrict__ wlo) {
    const int gid = blockIdx.x * 256 + threadIdx.x;            // 0..65535
    const float4 v = *(const float4*)(W + (size_t)gid * 4);
    unsigned int h0, l0, h1, l1;
    split_pair(v.x, v.y, h0, l0);
    split_pair(v.z, v.w, h1, l1);
    ((uint2*)whi)[gid] = make_uint2(h0, h1);
    ((uint2*)wlo)[gid] = make_uint2(l0, l1);
}

template <bool PRE>
__global__ __launch_bounds__(256, 4)
void router_mfma(const float* __restrict__ x,
                 const unsigned short* __restrict__ whi,
                 const unsigned short* __restrict__ wlo,
                 const float* __restrict__ Wf,
                 float* __restrict__ out)
{
    __shared__ float lgt[16 * 68];     // 16 tokens x (64 logits + m,inv + pad)
    const int tid  = threadIdx.x;
    const int lane = tid & 63;
    const int wid  = __builtin_amdgcn_readfirstlane(tid >> 6); // expert group 0..3
    const int c    = lane & 15;
    const int q    = lane >> 4;
    const int t0   = blockIdx.x * 16;

    const float* ap = x + (size_t)(t0 + c) * DIM + q * 8;      // A: token row c
    const int er = wid * 16 + c;                               // B: expert row

    f32x4 acc = {0.f, 0.f, 0.f, 0.f};

    if (PRE) {
        const unsigned short* hp = whi + (size_t)er * DIM + q * 8;
        const unsigned short* lp = wlo + (size_t)er * DIM + q * 8;
        // two chunk-sets in flight (depth-2 prefetch), unroll-2 K loop
        float4 xa0 = *(const float4*)(ap);
        float4 xa1 = *(const float4*)(ap + 4);
        short8 wh0 = *(const short8*)(hp);
        short8 wl0 = *(const short8*)(lp);
        float4 xb0 = *(const float4*)(ap + 32);
        float4 xb1 = *(const float4*)(ap + 36);
        short8 wh1 = *(const short8*)(hp + 32);
        short8 wl1 = *(const short8*)(lp + 32);
        for (int it = 0; it < DIM / 64 - 1; ++it) {
            ap += 64; hp += 64; lp += 64;
            float4 n0 = *(const float4*)(ap);
            float4 n1 = *(const float4*)(ap + 4);
            short8 nh = *(const short8*)(hp);
            short8 nl = *(const short8*)(lp);
            mfma3(acc, xa0, xa1, wh0, wl0);
            xa0 = n0; xa1 = n1; wh0 = nh; wl0 = nl;
            float4 m0 = *(const float4*)(ap + 32);
            float4 m1 = *(const float4*)(ap + 36);
            short8 mh = *(const short8*)(hp + 32);
            short8 ml = *(const short8*)(lp + 32);
            mfma3(acc, xb0, xb1, wh1, wl1);
            xb0 = m0; xb1 = m1; wh1 = mh; wl1 = ml;
        }
        mfma3(acc, xa0, xa1, wh0, wl0);
        mfma3(acc, xb0, xb1, wh1, wl1);
    } else {
        // fallback: split W on the fly (ws too small)
        const float* wp = Wf + (size_t)er * DIM + q * 8;
        float4 xa0 = *(const float4*)(ap), xa1 = *(const float4*)(ap + 4);
        float4 wa0 = *(const float4*)(wp), wa1 = *(const float4*)(wp + 4);
        for (int k = 32; k < DIM; k += 32) {
            ap += 32; wp += 32;
            float4 n0 = *(const float4*)(ap), n1 = *(const float4*)(ap + 4);
            float4 p0 = *(const float4*)(wp), p1 = *(const float4*)(wp + 4);
            short8 wh, wl;
            split8(wa0, wa1, wh, wl);
            mfma3(acc, xa0, xa1, wh, wl);
            xa0 = n0; xa1 = n1; wa0 = p0; wa1 = p1;
        }
        short8 wh, wl;
        split8(wa0, wa1, wh, wl);
        mfma3(acc, xa0, xa1, wh, wl);
    }

    // ---- epilogue ----
    // C/D layout (m89/m91): col(expert-in-group)=lane&15, row(token)=q*4+reg
#pragma unroll
    for (int r = 0; r < 4; ++r)
        lgt[(q * 4 + r) * 68 + wid * 16 + c] = acc[r];
    __syncthreads();

    if (tid < 16) {
        float* row = lgt + tid * 68;
        float m = -3.0e38f;
#pragma unroll
        for (int e4 = 0; e4 < NE; e4 += 4) {
            float4 v = *(const float4*)(row + e4);
            m = fmaxf(m, fmaxf(fmaxf(v.x, v.y), fmaxf(v.z, v.w)));
        }
        float sum = 0.f, v1 = -3.0e38f, v2 = -3.0e38f;
        int i1 = 0, i2 = 0;
#pragma unroll
        for (int e4 = 0; e4 < NE; e4 += 4) {
            float4 v = *(const float4*)(row + e4);
            sum += __expf(v.x - m) + __expf(v.y - m) + __expf(v.z - m) + __expf(v.w - m);
            const float* pv = &v.x;
#pragma unroll
            for (int j = 0; j < 4; ++j) {        // ascending e => lax.top_k tie-break
                const float p = pv[j];
                const int e = e4 + j;
                if (p > v1)      { v2 = v1; i2 = i1; v1 = p; i1 = e; }
                else if (p > v2) { v2 = p;  i2 = e; }
            }
        }
        const float inv = 1.f / sum;
        row[64] = m; row[65] = inv;
        const int t = t0 + tid;
        out[IDX_OFF + (size_t)t * 2]     = (float)i1;
        out[IDX_OFF + (size_t)t * 2 + 1] = (float)i2;
        out[VAL_OFF + (size_t)t * 2]     = __expf(v1 - m) * inv;
        out[VAL_OFF + (size_t)t * 2 + 1] = __expf(v2 - m) * inv;
    }
    __syncthreads();
    {   // coalesced probs write: block writes 16*64 floats contiguously
        const int tr = tid >> 4;
        const int e4 = (tid & 15) * 4;
        const float m = lgt[tr * 68 + 64], inv = lgt[tr * 68 + 65];
        const float4 v = *(const float4*)(lgt + tr * 68 + e4);
        float4 p;
        p.x = __expf(v.x - m) * inv;
        p.y = __expf(v.y - m) * inv;
        p.z = __expf(v.z - m) * inv;
        p.w = __expf(v.w - m) * inv;
        *(float4*)(out + (size_t)(t0 + tr) * NE + e4) = p;
    }
}

extern "C" void kernel_launch(void* const* d_in, const int* in_sizes, int n_in,
                              void* d_out, int out_size, void* d_ws, size_t ws_size,
                              hipStream_t stream) {
    const float* x = (const float*)d_in[0];
    const float* W = (const float*)d_in[1];
    float* out = (float*)d_out;
    (void)in_sizes; (void)n_in; (void)out_size;

    if (ws_size >= (size_t)WELTS * 4) {
        unsigned int* whi = (unsigned int*)d_ws;
        unsigned int* wlo = whi + WELTS / 2;
        wconv_kernel<<<WELTS / 4 / 256, 256, 0, stream>>>(W, whi, wlo);
        router_mfma<true><<<TOK / 16, 256, 0, stream>>>(
            x, (const unsigned short*)whi, (const unsigned short*)wlo, W, out);
    } else {
        router_mfma<false><<<TOK / 16, 256, 0, stream>>>(x, nullptr, nullptr, W, out);
    }
}

// Round 4
// 422.899 us; speedup vs baseline: 2.8615x; 1.1935x over previous
//
#include <hip/hip_runtime.h>

// TopKRouter: B=4,S=4096,D=4096,E=64,K=2 (tokens=16384)
// R4: LDS-staged split-bf16 MFMA pipeline.
//   - R3 was L2-transaction-bound (~2 GB L2 traffic: no staging, W re-read
//     per wave). R4 stages x (fp32) and W (pre-split bf16 hi/lo, fragment-
//     major) through LDS via global_load_lds(16B), triple-buffered.
//   - Raw `s_waitcnt vmcnt(4); s_barrier` keeps next tile's loads in flight
//     across the barrier (__syncthreads would drain vmcnt(0)).
//   - Block = 512 thr / 8 waves = 64 tok x 64 exp; wave = 16 tok x 32 exp
//     (2x mfma_f32_16x16x32_bf16, 3 MFMAs per chunk: hi*HI+lo*HI+hi*LO).
//   - x LDS layout XOR-swizzled (m ^ (tok&7)) at the *source* address so
//     A-frag ds_read_b128 is conflict-free (dest must be lane-contiguous).

#define TOK 16384
#define DIM 4096
#define NE  64
#define BK  64
#define NT  (DIM / BK)           // 64 K-tiles
#define IDX_OFF (TOK * NE)
#define VAL_OFF (IDX_OFF + TOK * 2)

typedef __attribute__((ext_vector_type(8))) short short8;
typedef __attribute__((ext_vector_type(4))) float f32x4;
union pk8u { unsigned int u[4]; short8 s; };

__device__ __forceinline__ unsigned int pack_hi(float fa, float fb) {
    return __builtin_amdgcn_perm(__float_as_uint(fb), __float_as_uint(fa), 0x07060302u);
}
__device__ __forceinline__ unsigned int pack_lo(float fa, float fb) {
    float la = fa - __uint_as_float(__float_as_uint(fa) & 0xffff0000u);  // exact
    float lb = fb - __uint_as_float(__float_as_uint(fb) & 0xffff0000u);  // exact
    return __builtin_amdgcn_perm(__float_as_uint(lb), __float_as_uint(la), 0x07060302u);
}
__device__ __forceinline__ void split8(const float4 v0, const float4 v1,
                                       short8& hi, short8& lo) {
    pk8u h, l;
    h.u[0] = pack_hi(v0.x, v0.y); l.u[0] = pack_lo(v0.x, v0.y);
    h.u[1] = pack_hi(v0.z, v0.w); l.u[1] = pack_lo(v0.z, v0.w);
    h.u[2] = pack_hi(v1.x, v1.y); l.u[2] = pack_lo(v1.x, v1.y);
    h.u[3] = pack_hi(v1.z, v1.w); l.u[3] = pack_lo(v1.z, v1.w);
    hi = h.s; lo = l.s;
}

// W -> fragment-major packed bf16 hi/lo in ws.
// Unit layout: ws unit index r = t*16 + (c*8 + g*2 + h); within unit:
// lane l (0..63), 8 bf16 = W[e = g*16 + (l&15)][t*64 + c*32 + (l>>4)*8 + j]
__global__ __launch_bounds__(256)
void wconv_kernel(const float* __restrict__ W, unsigned short* __restrict__ ws) {
    const int gid = blockIdx.x * 256 + threadIdx.x;   // 0..65535
    const int l = gid & 63;
    const int r = gid >> 6;
    const int h = r & 1;
    const int g = (r >> 1) & 3;
    const int c = (r >> 3) & 1;
    const int t = r >> 4;                              // 0..63
    const int e = g * 16 + (l & 15);
    const int k = t * 64 + c * 32 + (l >> 4) * 8;
    const float4 va = *(const float4*)(W + (size_t)e * DIM + k);
    const float4 vb = *(const float4*)(W + (size_t)e * DIM + k + 4);
    pk8u o;
    if (h == 0) {                                      // wave-uniform branch
        o.u[0] = pack_hi(va.x, va.y); o.u[1] = pack_hi(va.z, va.w);
        o.u[2] = pack_hi(vb.x, vb.y); o.u[3] = pack_hi(vb.z, vb.w);
    } else {
        o.u[0] = pack_lo(va.x, va.y); o.u[1] = pack_lo(va.z, va.w);
        o.u[2] = pack_lo(vb.x, vb.y); o.u[3] = pack_lo(vb.z, vb.w);
    }
    ((uint4*)ws)[gid] = *(uint4*)&o.u[0];
}

__global__ __launch_bounds__(512)
void router_mfma(const float* __restrict__ x,
                 const unsigned short* __restrict__ wsg,
                 float* __restrict__ out)
{
    __shared__ __align__(16) float          xs[3 * 4096];   // 3 x 16 KB
    __shared__ __align__(16) unsigned short wls[3 * 8192];  // 3 x 16 KB
    __shared__ __align__(16) float          lgt[64 * 68];   // 17408 B

    const int tid  = threadIdx.x;
    const int lane = tid & 63;
    const int wid  = __builtin_amdgcn_readfirstlane(tid >> 6);
    const int t0   = blockIdx.x * 64;
    const int c16  = lane & 15;
    const int q    = lane >> 4;
    const int tp   = wid & 3;      // token position (16-row group)
    const int eh   = wid >> 2;     // expert half (g = eh*2 + g2)

    // stage tile tt into buffer b: 4 global_load_lds(16B) per wave
    auto issue = [&](int tt, int b) {
#pragma unroll
        for (int i = 0; i < 2; ++i) {                  // x units
            const int u   = wid * 2 + i;
            const int p   = u * 64 + lane;             // chunk id 0..1023
            const int tok = p >> 4;
            const int m   = (p & 15) ^ (tok & 7);      // XOR source swizzle
            const float* src = x + (size_t)(t0 + tok) * DIM + tt * BK + m * 4;
            __builtin_amdgcn_global_load_lds(
                (const __attribute__((address_space(1))) unsigned int*)src,
                (__attribute__((address_space(3))) unsigned int*)&xs[b * 4096 + u * 256],
                16, 0, 0);
        }
#pragma unroll
        for (int i = 0; i < 2; ++i) {                  // W units (frag-major, contiguous)
            const int v = wid * 2 + i;
            const unsigned short* src = wsg + ((size_t)(tt * 16 + v) * 64 + lane) * 8;
            __builtin_amdgcn_global_load_lds(
                (const __attribute__((address_space(1))) unsigned int*)src,
                (__attribute__((address_space(3))) unsigned int*)&wls[b * 8192 + v * 512],
                16, 0, 0);
        }
    };

    f32x4 acc0 = {0.f, 0.f, 0.f, 0.f};
    f32x4 acc1 = {0.f, 0.f, 0.f, 0.f};

    issue(0, 0);
    issue(1, 1);
    int b = 0;
    for (int t = 0; t < NT; ++t) {
        // wait only tile t's 4 loads (oldest); tile t+1's stay in flight
        if (t < NT - 1)
            asm volatile("s_waitcnt vmcnt(4) lgkmcnt(0)\n\ts_barrier" ::: "memory");
        else
            asm volatile("s_waitcnt vmcnt(0) lgkmcnt(0)\n\ts_barrier" ::: "memory");
        if (t + 2 < NT) issue(t + 2, (b + 2) % 3);     // into buffer of tile t-1 (free)

        const float*          xb = &xs[b * 4096];
        const unsigned short* wb = &wls[b * 8192];
#pragma unroll
        for (int c = 0; c < 2; ++c) {                  // 2 K=32 chunks
            const int tokA = tp * 16 + c16;
            const int m1   = c * 8 + q * 2;
            const float4 a0 = *(const float4*)(xb + (tokA * 16 + ( m1      ^ (tokA & 7))) * 4);
            const float4 a1 = *(const float4*)(xb + (tokA * 16 + ((m1 + 1) ^ (tokA & 7))) * 4);
            short8 ah, al;
            split8(a0, a1, ah, al);
#pragma unroll
            for (int g2 = 0; g2 < 2; ++g2) {
                const int g = eh * 2 + g2;
                const int vb_ = ((c * 4 + g) * 2) * 512 + lane * 8;
                const short8 bh = *(const short8*)(wb + vb_);
                const short8 bl = *(const short8*)(wb + vb_ + 512);
                f32x4& A = g2 ? acc1 : acc0;
                A = __builtin_amdgcn_mfma_f32_16x16x32_bf16(ah, bh, A, 0, 0, 0);
                A = __builtin_amdgcn_mfma_f32_16x16x32_bf16(al, bh, A, 0, 0, 0);
                A = __builtin_amdgcn_mfma_f32_16x16x32_bf16(ah, bl, A, 0, 0, 0);
            }
        }
        b = (b + 1) % 3;
    }

    // ---- epilogue: logits -> LDS, softmax + top-2 ----
    // C/D layout (m89-verified): col = lane&15 (expert in group), row = q*4+reg
#pragma unroll
    for (int r = 0; r < 4; ++r) {
        lgt[(tp * 16 + q * 4 + r) * 68 + (eh * 2 + 0) * 16 + c16] = acc0[r];
        lgt[(tp * 16 + q * 4 + r) * 68 + (eh * 2 + 1) * 16 + c16] = acc1[r];
    }
    __syncthreads();

    if (tid < 64) {
        const int tkn = t0 + tid;
        float* row = lgt + tid * 68;
        float m = -3.0e38f;
#pragma unroll
        for (int e4 = 0; e4 < NE; e4 += 4) {
            const float4 v = *(const float4*)(row + e4);
            m = fmaxf(m, fmaxf(fmaxf(v.x, v.y), fmaxf(v.z, v.w)));
        }
        float sum = 0.f, v1 = -3.0e38f, v2 = -3.0e38f;
        int i1 = 0, i2 = 0;
#pragma unroll
        for (int e4 = 0; e4 < NE; e4 += 4) {
            const float4 v = *(const float4*)(row + e4);
            sum += __expf(v.x - m) + __expf(v.y - m) + __expf(v.z - m) + __expf(v.w - m);
            const float* pv = &v.x;
#pragma unroll
            for (int j = 0; j < 4; ++j) {              // ascending e => lax.top_k tie-break
                const float p = pv[j];
                const int e = e4 + j;
                if (p > v1)      { v2 = v1; i2 = i1; v1 = p; i1 = e; }
                else if (p > v2) { v2 = p;  i2 = e; }
            }
        }
        const float inv = 1.f / sum;
        row[64] = m; row[65] = inv;
        out[IDX_OFF + (size_t)tkn * 2]     = (float)i1;
        out[IDX_OFF + (size_t)tkn * 2 + 1] = (float)i2;
        out[VAL_OFF + (size_t)tkn * 2]     = __expf(v1 - m) * inv;
        out[VAL_OFF + (size_t)tkn * 2 + 1] = __expf(v2 - m) * inv;
    }
    __syncthreads();

    {   // coalesced probs write: 512 threads x 8 floats = 64 tok x 64 exp
        const int row = tid >> 3;
        const int e8  = (tid & 7) * 8;
        const float m   = lgt[row * 68 + 64];
        const float inv = lgt[row * 68 + 65];
        const float4 v0 = *(const float4*)(lgt + row * 68 + e8);
        const float4 v1 = *(const float4*)(lgt + row * 68 + e8 + 4);
        float4 p0, p1;
        p0.x = __expf(v0.x - m) * inv; p0.y = __expf(v0.y - m) * inv;
        p0.z = __expf(v0.z - m) * inv; p0.w = __expf(v0.w - m) * inv;
        p1.x = __expf(v1.x - m) * inv; p1.y = __expf(v1.y - m) * inv;
        p1.z = __expf(v1.z - m) * inv; p1.w = __expf(v1.w - m) * inv;
        float* dst = out + (size_t)(t0 + row) * NE + e8;
        *(float4*)dst       = p0;
        *(float4*)(dst + 4) = p1;
    }
}

// correctness-only fallback if ws is too small (should not trigger)
__global__ __launch_bounds__(64)
void fallback_kernel(const float* __restrict__ x, const float* __restrict__ W,
                     float* __restrict__ out) {
    const int tk = blockIdx.x * 64 + threadIdx.x;
    const float* xr = x + (size_t)tk * DIM;
    float lg[NE];
    float m = -3.0e38f;
    for (int e = 0; e < NE; ++e) {
        const float* wr = W + (size_t)e * DIM;
        float s = 0.f;
        for (int d = 0; d < DIM; d += 4) {
            const float4 a = *(const float4*)(xr + d);
            const float4 bb = *(const float4*)(wr + d);
            s += a.x * bb.x + a.y * bb.y + a.z * bb.z + a.w * bb.w;
        }
        lg[e] = s; m = fmaxf(m, s);
    }
    float sum = 0.f;
    for (int e = 0; e < NE; ++e) sum += __expf(lg[e] - m);
    const float inv = 1.f / sum;
    float v1 = -3.0e38f, v2 = -3.0e38f; int i1 = 0, i2 = 0;
    for (int e = 0; e < NE; ++e) {
        const float p = __expf(lg[e] - m) * inv;
        out[(size_t)tk * NE + e] = p;
        if (p > v1)      { v2 = v1; i2 = i1; v1 = p; i1 = e; }
        else if (p > v2) { v2 = p;  i2 = e; }
    }
    out[IDX_OFF + (size_t)tk * 2]     = (float)i1;
    out[IDX_OFF + (size_t)tk * 2 + 1] = (float)i2;
    out[VAL_OFF + (size_t)tk * 2]     = v1;
    out[VAL_OFF + (size_t)tk * 2 + 1] = v2;
}

extern "C" void kernel_launch(void* const* d_in, const int* in_sizes, int n_in,
                              void* d_out, int out_size, void* d_ws, size_t ws_size,
                              hipStream_t stream) {
    const float* x = (const float*)d_in[0];
    const float* W = (const float*)d_in[1];
    float* out = (float*)d_out;
    (void)in_sizes; (void)n_in; (void)out_size;

    if (ws_size >= (size_t)NE * DIM * 2 * 2) {         // 1 MB hi+lo bf16
        wconv_kernel<<<256, 256, 0, stream>>>(W, (unsigned short*)d_ws);
        router_mfma<<<TOK / 64, 512, 0, stream>>>(x, (const unsigned short*)d_ws, out);
    } else {
        fallback_kernel<<<TOK / 64, 64, 0, stream>>>(x, W, out);
    }
}